// Round 3
// baseline (913.124 us; speedup 1.0000x reference)
//
#include <hip/hip_runtime.h>
#include <math.h>

#define N_NODES 100000
#define N_EDGES 3200000

// Bucketed counting sort parameters: 128 nodes per bucket.
#define NPB   128
#define NB    782            // ceil(100000/128)
#define BCAP  5120           // mean 4096 edges/bucket, +16 sigma margin (uniform graph)

__device__ __forceinline__ float gelu_tanh(float x) {
    // jax.nn.gelu default approximate=True (tanh form)
    const float c = 0.7978845608028654f;  // sqrt(2/pi)
    float t = tanhf(c * (x + 0.044715f * x * x * x));
    return 0.5f * x * (1.0f + t);
}

// Distinguish int64 vs int32 edge_index layout: under little-endian int64 with
// values in [0, 1e5), every odd dword is 0. Under int32 these are random src
// values; P(all 64 == 0) ~ 0.
__global__ void detect_kernel(const unsigned int* __restrict__ ei, int* __restrict__ flag) {
    unsigned int v = ei[2 * threadIdx.x + 1];
    unsigned long long m = __ballot(v != 0u);
    if (threadIdx.x == 0) flag[0] = (m != 0ull) ? 1 : 0;  // 1 => int32 layout
}

__device__ __forceinline__ int load_idx(const void* ei, int f, size_t pos) {
    if (f) return ((const int*)ei)[pos];
    return (int)((const long long*)ei)[pos];
}

// Pass 1: partition edges into dst-buckets; packed entry = src | local_dst<<17.
__global__ void part_kernel(const void* __restrict__ ei, const int* __restrict__ flag,
                            int* __restrict__ gcnt, int* __restrict__ btmp) {
    int e = blockIdx.x * blockDim.x + threadIdx.x;
    if (e >= N_EDGES) return;
    int f = flag[0];
    int s = load_idx(ei, f, e);
    int d = load_idx(ei, f, (size_t)N_EDGES + e);
    int b = d >> 7;
    int pos = atomicAdd(&gcnt[b], 1);
    if (pos < BCAP) btmp[(size_t)b * BCAP + pos] = s | ((d & (NPB - 1)) << 17);
}

// Exclusive scan over the 782 bucket totals -> bbase; also off[N] = E.
__global__ void bscan_kernel(const int* __restrict__ gcnt, int* __restrict__ bbase,
                             int* __restrict__ off) {
    __shared__ int sh[1024];
    int t = threadIdx.x;
    int v = (t < NB) ? min(gcnt[t], BCAP) : 0;
    sh[t] = v;
    __syncthreads();
    int val = v;
    for (int o = 1; o < 1024; o <<= 1) {
        int add = (t >= o) ? sh[t - o] : 0;
        __syncthreads();
        val += add;
        sh[t] = val;
        __syncthreads();
    }
    if (t < NB) bbase[t] = val - v;  // exclusive
    if (t == NB - 1) off[N_NODES] = val;  // == N_EDGES
}

// Pass 2: per-bucket LDS counting sort -> coalesced csr segment; also emits
// per-node off[] and dinv[].
__global__ void build_kernel(const int* __restrict__ gcnt, const int* __restrict__ bbase,
                             const int* __restrict__ btmp, int* __restrict__ csr,
                             int* __restrict__ off, float* __restrict__ dinv) {
    __shared__ int lcnt[NPB];
    __shared__ int lcur[NPB];
    __shared__ int ssc[NPB];
    __shared__ int stage[BCAP];
    int b = blockIdx.x;
    int t = threadIdx.x;
    int cnt = min(gcnt[b], BCAP);
    int base = bbase[b];
    if (t < NPB) lcnt[t] = 0;
    __syncthreads();
    const int* bt = btmp + (size_t)b * BCAP;
    for (int i = t; i < cnt; i += 256) atomicAdd(&lcnt[bt[i] >> 17], 1);
    __syncthreads();
    // exclusive scan of lcnt[0..NPB)
    int c = (t < NPB) ? lcnt[t] : 0;
    if (t < NPB) ssc[t] = c;
    __syncthreads();
    int val = c;
    for (int o = 1; o < NPB; o <<= 1) {
        int add = (t < NPB && t >= o) ? ssc[t - o] : 0;
        __syncthreads();
        if (t < NPB) { val += add; ssc[t] = val; }
        __syncthreads();
    }
    if (t < NPB) {
        int excl = val - c;
        lcur[t] = excl;
        int node = b * NPB + t;
        if (node < N_NODES) {
            off[node] = base + excl;
            dinv[node] = rsqrtf((float)c + 1.0f);  // +1 = appended self-loop
        }
    }
    __syncthreads();
    for (int i = t; i < cnt; i += 256) {
        int e = bt[i];
        int p = atomicAdd(&lcur[e >> 17], 1);
        stage[p] = e & 0x1FFFF;
    }
    __syncthreads();
    for (int i = t; i < cnt; i += 256) csr[base + i] = stage[i];
}

// Layer 1 pre-propagation: h2[n] = dinv[n] * (X[n] @ W1), padded to stride 12.
__global__ void node1_kernel(const float* __restrict__ X, const float* __restrict__ W,
                             const float* __restrict__ dinv, float* __restrict__ h2) {
    int n = blockIdx.x * blockDim.x + threadIdx.x;
    if (n >= N_NODES) return;
    float x[11];
#pragma unroll
    for (int i = 0; i < 11; i++) x[i] = X[n * 11 + i];
    float di = dinv[n];
#pragma unroll
    for (int j = 0; j < 11; j++) {
        float a = 0.0f;
#pragma unroll
        for (int i = 0; i < 11; i++) a += x[i] * W[i * 11 + j];
        h2[n * 12 + j] = di * a;
    }
    h2[n * 12 + 11] = 0.0f;
}

// Fused gather + finalize + gelu + next-layer GEMM. 4 lanes per node.
template <int OUT>
__global__ void mid_kernel(const int* __restrict__ off, const int* __restrict__ csr,
                           const float* __restrict__ h2in, const float* __restrict__ bias,
                           const float* __restrict__ W, const float* __restrict__ dinv,
                           float* __restrict__ h2out) {
    int tid = blockIdx.x * blockDim.x + threadIdx.x;
    int n = tid >> 2;
    int p = tid & 3;
    if (n >= N_NODES) return;
    int lo = off[n], hi = off[n + 1];
    float a[11];
    if (p == 0) {  // self-loop term
        const float4* sp = (const float4*)(h2in + (size_t)n * 12);
        float4 u0 = sp[0], u1 = sp[1], u2 = sp[2];
        a[0] = u0.x; a[1] = u0.y; a[2] = u0.z; a[3] = u0.w;
        a[4] = u1.x; a[5] = u1.y; a[6] = u1.z; a[7] = u1.w;
        a[8] = u2.x; a[9] = u2.y; a[10] = u2.z;
    } else {
#pragma unroll
        for (int i = 0; i < 11; i++) a[i] = 0.0f;
    }
    for (int e = lo + p; e < hi; e += 4) {
        int s = csr[e];
        const float4* hp = (const float4*)(h2in + (size_t)s * 12);
        float4 v0 = hp[0], v1 = hp[1], v2 = hp[2];
        a[0] += v0.x; a[1] += v0.y; a[2] += v0.z; a[3] += v0.w;
        a[4] += v1.x; a[5] += v1.y; a[6] += v1.z; a[7] += v1.w;
        a[8] += v2.x; a[9] += v2.y; a[10] += v2.z;
    }
#pragma unroll
    for (int i = 0; i < 11; i++) {
        a[i] += __shfl_xor(a[i], 1);
        a[i] += __shfl_xor(a[i], 2);
    }
    float di = dinv[n];
    float t[11];
#pragma unroll
    for (int i = 0; i < 11; i++) t[i] = gelu_tanh(di * a[i] + bias[i]);
#pragma unroll
    for (int j0 = 0; j0 < 3; j0++) {
        int j = p + 4 * j0;
        if (j >= 12) continue;
        float o = 0.0f;
        if (j < OUT) {
            float acc = 0.0f;
#pragma unroll
            for (int i = 0; i < 11; i++) acc += t[i] * W[i * OUT + j];
            o = di * acc;
        }
        h2out[(size_t)n * 12 + j] = o;
    }
}

// Final layer: gather + finalize + log_softmax (10 classes). 4 lanes per node.
__global__ void final_kernel(const int* __restrict__ off, const int* __restrict__ csr,
                             const float* __restrict__ h2in, const float* __restrict__ bias,
                             const float* __restrict__ dinv, float* __restrict__ out) {
    int tid = blockIdx.x * blockDim.x + threadIdx.x;
    int n = tid >> 2;
    int p = tid & 3;
    if (n >= N_NODES) return;
    int lo = off[n], hi = off[n + 1];
    float a[10];
    if (p == 0) {
        const float4* sp = (const float4*)(h2in + (size_t)n * 12);
        float4 u0 = sp[0], u1 = sp[1], u2 = sp[2];
        a[0] = u0.x; a[1] = u0.y; a[2] = u0.z; a[3] = u0.w;
        a[4] = u1.x; a[5] = u1.y; a[6] = u1.z; a[7] = u1.w;
        a[8] = u2.x; a[9] = u2.y;
    } else {
#pragma unroll
        for (int i = 0; i < 10; i++) a[i] = 0.0f;
    }
    for (int e = lo + p; e < hi; e += 4) {
        int s = csr[e];
        const float4* hp = (const float4*)(h2in + (size_t)s * 12);
        float4 v0 = hp[0], v1 = hp[1], v2 = hp[2];
        a[0] += v0.x; a[1] += v0.y; a[2] += v0.z; a[3] += v0.w;
        a[4] += v1.x; a[5] += v1.y; a[6] += v1.z; a[7] += v1.w;
        a[8] += v2.x; a[9] += v2.y;
    }
#pragma unroll
    for (int i = 0; i < 10; i++) {
        a[i] += __shfl_xor(a[i], 1);
        a[i] += __shfl_xor(a[i], 2);
    }
    float di = dinv[n];
    float t[10];
    float m = -1e30f;
#pragma unroll
    for (int j = 0; j < 10; j++) {
        t[j] = di * a[j] + bias[j];
        m = fmaxf(m, t[j]);
    }
    float s = 0.0f;
#pragma unroll
    for (int j = 0; j < 10; j++) s += expf(t[j] - m);
    float ls = logf(s);
    for (int j = p; j < 10; j += 4) out[(size_t)n * 10 + j] = t[j] - m - ls;
}

extern "C" void kernel_launch(void* const* d_in, const int* in_sizes, int n_in,
                              void* d_out, int out_size, void* d_ws, size_t ws_size,
                              hipStream_t stream) {
    const float* X  = (const float*)d_in[0];
    const void*  ei = d_in[1];
    const float* W1 = (const float*)d_in[2];
    const float* b1 = (const float*)d_in[3];
    const float* W2 = (const float*)d_in[4];
    const float* b2 = (const float*)d_in[5];
    const float* W3 = (const float*)d_in[6];
    const float* b3 = (const float*)d_in[7];
    float* out = (float*)d_out;

    const size_t N = N_NODES;
    const size_t E = N_EDGES;
    // Workspace layout. h2a first => 16B alignment for float4 loads; every
    // region below is a multiple of 4 dwords where alignment matters.
    float* h2a  = (float*)d_ws;            // [12N]
    float* h2b  = h2a + 12 * N;            // [12N]
    int*   csr  = (int*)(h2b + 12 * N);    // [E]
    int*   btmp = csr + E;                 // [NB*BCAP] = 4,003,840
    int*   off  = btmp + (size_t)NB * BCAP;// [N+4]
    float* dinv = (float*)(off + N + 4);   // [N]
    int*   gcnt = (int*)(dinv + N);        // [NB]
    int*   bbase= gcnt + NB;               // [NB+2]
    int*   flag = bbase + NB + 2;          // [1]

    hipMemsetAsync(gcnt, 0, NB * sizeof(int), stream);

    const int eb = (N_EDGES + 255) / 256;
    const int nb = (N_NODES + 255) / 256;
    const int gb = (4 * N_NODES + 255) / 256;

    detect_kernel<<<1, 64, 0, stream>>>((const unsigned int*)ei, flag);
    part_kernel<<<eb, 256, 0, stream>>>(ei, flag, gcnt, btmp);
    bscan_kernel<<<1, 1024, 0, stream>>>(gcnt, bbase, off);
    build_kernel<<<NB, 256, 0, stream>>>(gcnt, bbase, btmp, csr, off, dinv);

    node1_kernel<<<nb, 256, 0, stream>>>(X, W1, dinv, h2a);
    mid_kernel<11><<<gb, 256, 0, stream>>>(off, csr, h2a, b1, W2, dinv, h2b);
    mid_kernel<10><<<gb, 256, 0, stream>>>(off, csr, h2b, b2, W3, dinv, h2a);
    final_kernel<<<gb, 256, 0, stream>>>(off, csr, h2a, b3, dinv, out);
}

// Round 4
// 214.648 us; speedup vs baseline: 4.2541x; 4.2541x over previous
//
#include <hip/hip_runtime.h>
#include <math.h>

#define N_NODES 100000
#define N_EDGES 3200000

// Bucketed counting sort: 128 nodes per bucket.
#define NPB   128
#define NB    782            // ceil(100000/128)
#define BCAP  5120           // LDS stage bound in build (mean 4096, +16 sigma)
#define KB    256            // partition blocks
#define CH    12500          // edges per partition block (N_EDGES / KB)

__device__ __forceinline__ float gelu_tanh(float x) {
    // jax.nn.gelu default approximate=True (tanh form)
    const float c = 0.7978845608028654f;  // sqrt(2/pi)
    float t = tanhf(c * (x + 0.044715f * x * x * x));
    return 0.5f * x * (1.0f + t);
}

// Distinguish int64 vs int32 edge_index layout: under little-endian int64 with
// values in [0, 1e5), every odd dword is 0. Under int32 these are random src
// values; P(all 64 == 0) ~ 0.
__global__ void detect_kernel(const unsigned int* __restrict__ ei, int* __restrict__ flag) {
    unsigned int v = ei[2 * threadIdx.x + 1];
    unsigned long long m = __ballot(v != 0u);
    if (threadIdx.x == 0) flag[0] = (m != 0ull) ? 1 : 0;  // 1 => int32 layout
}

__device__ __forceinline__ int load_idx(const void* ei, int f, size_t pos) {
    if (f) return ((const int*)ei)[pos];
    return (int)((const long long*)ei)[pos];
}

// Pass A: per-block bucket histogram -> bcnt[b*KB + k]. No global atomics.
__global__ void cnt_kernel(const void* __restrict__ ei, const int* __restrict__ flag,
                           int* __restrict__ bcnt) {
    __shared__ int lcnt[NB];
    int k = blockIdx.x, t = threadIdx.x;
    for (int b = t; b < NB; b += 256) lcnt[b] = 0;
    __syncthreads();
    int f = flag[0];
    int lo = k * CH, hi = min(lo + CH, N_EDGES);
    for (int e = lo + t; e < hi; e += 256) {
        int d = load_idx(ei, f, (size_t)N_EDGES + e);
        atomicAdd(&lcnt[d >> 7], 1);
    }
    __syncthreads();
    for (int b = t; b < NB; b += 256) bcnt[b * KB + k] = lcnt[b];
}

// Pass B1: per-bucket exclusive prefix over blocks, in place; tot[b] = sum.
__global__ void bprefix_kernel(int* __restrict__ bcnt, int* __restrict__ tot) {
    int b = blockIdx.x * blockDim.x + threadIdx.x;
    if (b >= NB) return;
    int run = 0;
    int base = b * KB;
    for (int k = 0; k < KB; k++) {
        int v = bcnt[base + k];
        bcnt[base + k] = run;
        run += v;
    }
    tot[b] = run;
}

// Pass B2: exclusive scan over bucket totals -> bbase; off[N] = E.
__global__ void bscan_kernel(const int* __restrict__ tot, int* __restrict__ bbase,
                             int* __restrict__ off) {
    __shared__ int sh[1024];
    int t = threadIdx.x;
    int v = (t < NB) ? tot[t] : 0;
    sh[t] = v;
    __syncthreads();
    int val = v;
    for (int o = 1; o < 1024; o <<= 1) {
        int add = (t >= o) ? sh[t - o] : 0;
        __syncthreads();
        val += add;
        sh[t] = val;
        __syncthreads();
    }
    if (t < NB) bbase[t] = val - v;
    if (t == NB - 1) off[N_NODES] = val;  // == N_EDGES
}

// Pass C: place each edge in its block's pre-claimed range (no global atomics).
// Packed entry = src | local_dst<<17.
__global__ void part2_kernel(const void* __restrict__ ei, const int* __restrict__ flag,
                             const int* __restrict__ boff, const int* __restrict__ bbase,
                             int* __restrict__ btmp) {
    __shared__ int lcnt[NB];
    __shared__ int lbase[NB];
    int k = blockIdx.x, t = threadIdx.x;
    for (int b = t; b < NB; b += 256) {
        lcnt[b] = 0;
        lbase[b] = bbase[b] + boff[b * KB + k];
    }
    __syncthreads();
    int f = flag[0];
    int lo = k * CH, hi = min(lo + CH, N_EDGES);
    for (int e = lo + t; e < hi; e += 256) {
        int s = load_idx(ei, f, e);
        int d = load_idx(ei, f, (size_t)N_EDGES + e);
        int b = d >> 7;
        int pos = atomicAdd(&lcnt[b], 1);
        btmp[lbase[b] + pos] = s | ((d & (NPB - 1)) << 17);
    }
}

// Pass D: per-bucket LDS counting sort -> coalesced csr segment; also emits
// per-node off[] and dinv[].
__global__ void build_kernel(const int* __restrict__ tot, const int* __restrict__ bbase,
                             const int* __restrict__ btmp, int* __restrict__ csr,
                             int* __restrict__ off, float* __restrict__ dinv) {
    __shared__ int lcnt[NPB];
    __shared__ int lcur[NPB];
    __shared__ int ssc[NPB];
    __shared__ int stage[BCAP];
    int b = blockIdx.x;
    int t = threadIdx.x;
    int cnt = min(tot[b], BCAP);
    int base = bbase[b];
    if (t < NPB) lcnt[t] = 0;
    __syncthreads();
    const int* bt = btmp + base;
    for (int i = t; i < cnt; i += 256) atomicAdd(&lcnt[bt[i] >> 17], 1);
    __syncthreads();
    // exclusive scan of lcnt[0..NPB)
    int c = (t < NPB) ? lcnt[t] : 0;
    if (t < NPB) ssc[t] = c;
    __syncthreads();
    int val = c;
    for (int o = 1; o < NPB; o <<= 1) {
        int add = (t < NPB && t >= o) ? ssc[t - o] : 0;
        __syncthreads();
        if (t < NPB) { val += add; ssc[t] = val; }
        __syncthreads();
    }
    if (t < NPB) {
        int excl = val - c;
        lcur[t] = excl;
        int node = b * NPB + t;
        if (node < N_NODES) {
            off[node] = base + excl;
            dinv[node] = rsqrtf((float)c + 1.0f);  // +1 = appended self-loop
        }
    }
    __syncthreads();
    for (int i = t; i < cnt; i += 256) {
        int e = bt[i];
        int p = atomicAdd(&lcur[e >> 17], 1);
        stage[p] = e & 0x1FFFF;
    }
    __syncthreads();
    for (int i = t; i < cnt; i += 256) csr[base + i] = stage[i];
}

// Layer 1 pre-propagation: h2[n] = dinv[n] * (X[n] @ W1), padded to stride 12.
__global__ void node1_kernel(const float* __restrict__ X, const float* __restrict__ W,
                             const float* __restrict__ dinv, float* __restrict__ h2) {
    int n = blockIdx.x * blockDim.x + threadIdx.x;
    if (n >= N_NODES) return;
    float x[11];
#pragma unroll
    for (int i = 0; i < 11; i++) x[i] = X[n * 11 + i];
    float di = dinv[n];
#pragma unroll
    for (int j = 0; j < 11; j++) {
        float a = 0.0f;
#pragma unroll
        for (int i = 0; i < 11; i++) a += x[i] * W[i * 11 + j];
        h2[n * 12 + j] = di * a;
    }
    h2[n * 12 + 11] = 0.0f;
}

// Fused gather + finalize + gelu + next-layer GEMM. 4 lanes per node.
template <int OUT>
__global__ void mid_kernel(const int* __restrict__ off, const int* __restrict__ csr,
                           const float* __restrict__ h2in, const float* __restrict__ bias,
                           const float* __restrict__ W, const float* __restrict__ dinv,
                           float* __restrict__ h2out) {
    int tid = blockIdx.x * blockDim.x + threadIdx.x;
    int n = tid >> 2;
    int p = tid & 3;
    if (n >= N_NODES) return;
    int lo = off[n], hi = off[n + 1];
    float a[11];
    if (p == 0) {  // self-loop term
        const float4* sp = (const float4*)(h2in + (size_t)n * 12);
        float4 u0 = sp[0], u1 = sp[1], u2 = sp[2];
        a[0] = u0.x; a[1] = u0.y; a[2] = u0.z; a[3] = u0.w;
        a[4] = u1.x; a[5] = u1.y; a[6] = u1.z; a[7] = u1.w;
        a[8] = u2.x; a[9] = u2.y; a[10] = u2.z;
    } else {
#pragma unroll
        for (int i = 0; i < 11; i++) a[i] = 0.0f;
    }
    for (int e = lo + p; e < hi; e += 4) {
        int s = csr[e];
        const float4* hp = (const float4*)(h2in + (size_t)s * 12);
        float4 v0 = hp[0], v1 = hp[1], v2 = hp[2];
        a[0] += v0.x; a[1] += v0.y; a[2] += v0.z; a[3] += v0.w;
        a[4] += v1.x; a[5] += v1.y; a[6] += v1.z; a[7] += v1.w;
        a[8] += v2.x; a[9] += v2.y; a[10] += v2.z;
    }
#pragma unroll
    for (int i = 0; i < 11; i++) {
        a[i] += __shfl_xor(a[i], 1);
        a[i] += __shfl_xor(a[i], 2);
    }
    float di = dinv[n];
    float t[11];
#pragma unroll
    for (int i = 0; i < 11; i++) t[i] = gelu_tanh(di * a[i] + bias[i]);
#pragma unroll
    for (int j0 = 0; j0 < 3; j0++) {
        int j = p + 4 * j0;
        if (j >= 12) continue;
        float o = 0.0f;
        if (j < OUT) {
            float acc = 0.0f;
#pragma unroll
            for (int i = 0; i < 11; i++) acc += t[i] * W[i * OUT + j];
            o = di * acc;
        }
        h2out[(size_t)n * 12 + j] = o;
    }
}

// Final layer: gather + finalize + log_softmax (10 classes). 4 lanes per node.
__global__ void final_kernel(const int* __restrict__ off, const int* __restrict__ csr,
                             const float* __restrict__ h2in, const float* __restrict__ bias,
                             const float* __restrict__ dinv, float* __restrict__ out) {
    int tid = blockIdx.x * blockDim.x + threadIdx.x;
    int n = tid >> 2;
    int p = tid & 3;
    if (n >= N_NODES) return;
    int lo = off[n], hi = off[n + 1];
    float a[10];
    if (p == 0) {
        const float4* sp = (const float4*)(h2in + (size_t)n * 12);
        float4 u0 = sp[0], u1 = sp[1], u2 = sp[2];
        a[0] = u0.x; a[1] = u0.y; a[2] = u0.z; a[3] = u0.w;
        a[4] = u1.x; a[5] = u1.y; a[6] = u1.z; a[7] = u1.w;
        a[8] = u2.x; a[9] = u2.y;
    } else {
#pragma unroll
        for (int i = 0; i < 10; i++) a[i] = 0.0f;
    }
    for (int e = lo + p; e < hi; e += 4) {
        int s = csr[e];
        const float4* hp = (const float4*)(h2in + (size_t)s * 12);
        float4 v0 = hp[0], v1 = hp[1], v2 = hp[2];
        a[0] += v0.x; a[1] += v0.y; a[2] += v0.z; a[3] += v0.w;
        a[4] += v1.x; a[5] += v1.y; a[6] += v1.z; a[7] += v1.w;
        a[8] += v2.x; a[9] += v2.y;
    }
#pragma unroll
    for (int i = 0; i < 10; i++) {
        a[i] += __shfl_xor(a[i], 1);
        a[i] += __shfl_xor(a[i], 2);
    }
    float di = dinv[n];
    float t[10];
    float m = -1e30f;
#pragma unroll
    for (int j = 0; j < 10; j++) {
        t[j] = di * a[j] + bias[j];
        m = fmaxf(m, t[j]);
    }
    float s = 0.0f;
#pragma unroll
    for (int j = 0; j < 10; j++) s += expf(t[j] - m);
    float ls = logf(s);
    for (int j = p; j < 10; j += 4) out[(size_t)n * 10 + j] = t[j] - m - ls;
}

extern "C" void kernel_launch(void* const* d_in, const int* in_sizes, int n_in,
                              void* d_out, int out_size, void* d_ws, size_t ws_size,
                              hipStream_t stream) {
    const float* X  = (const float*)d_in[0];
    const void*  ei = d_in[1];
    const float* W1 = (const float*)d_in[2];
    const float* b1 = (const float*)d_in[3];
    const float* W2 = (const float*)d_in[4];
    const float* b2 = (const float*)d_in[5];
    const float* W3 = (const float*)d_in[6];
    const float* b3 = (const float*)d_in[7];
    float* out = (float*)d_out;

    const size_t N = N_NODES;
    const size_t E = N_EDGES;
    // Workspace layout (regions kept 16B-aligned).
    float* h2a  = (float*)d_ws;             // [12N]
    float* h2b  = h2a + 12 * N;             // [12N]
    int*   csr  = (int*)(h2b + 12 * N);     // [E]
    int*   btmp = csr + E;                  // [E]
    int*   bcnt = btmp + E;                 // [NB*KB]  (becomes boff in place)
    int*   tot  = bcnt + (size_t)NB * KB;   // [NB+2 pad]
    int*   bbase= tot + NB + 2;             // [NB+2 pad]
    int*   off  = bbase + NB + 2;           // [N+4]
    float* dinv = (float*)(off + N + 4);    // [N]
    int*   flag = (int*)(dinv + N);         // [1]

    const int nb = (N_NODES + 255) / 256;
    const int gb = (4 * N_NODES + 255) / 256;

    detect_kernel<<<1, 64, 0, stream>>>((const unsigned int*)ei, flag);
    cnt_kernel<<<KB, 256, 0, stream>>>(ei, flag, bcnt);
    bprefix_kernel<<<(NB + 63) / 64, 64, 0, stream>>>(bcnt, tot);
    bscan_kernel<<<1, 1024, 0, stream>>>(tot, bbase, off);
    part2_kernel<<<KB, 256, 0, stream>>>(ei, flag, bcnt, bbase, btmp);
    build_kernel<<<NB, 256, 0, stream>>>(tot, bbase, btmp, csr, off, dinv);

    node1_kernel<<<nb, 256, 0, stream>>>(X, W1, dinv, h2a);
    mid_kernel<11><<<gb, 256, 0, stream>>>(off, csr, h2a, b1, W2, dinv, h2b);
    mid_kernel<10><<<gb, 256, 0, stream>>>(off, csr, h2b, b2, W3, dinv, h2a);
    final_kernel<<<gb, 256, 0, stream>>>(off, csr, h2a, b3, dinv, out);
}